// Round 1
// baseline (838.705 us; speedup 1.0000x reference)
//
#include <hip/hip_runtime.h>
#include <stdint.h>

#define N_NODES 100000
#define N_EDGES 3200000

// ---------------------------------------------------------------------------
// CSR build: counts -> row offsets (via atomic grab, order-free) -> fill slots
// ---------------------------------------------------------------------------

__global__ void pad_x_kernel(const float* __restrict__ x, float* __restrict__ xpad,
                             int* __restrict__ counts, int* __restrict__ total) {
    int i = blockIdx.x * blockDim.x + threadIdx.x;
    if (i == 0) *total = 0;
    if (i < N_NODES) {
        counts[i] = 0;
        const float* xr = x + (size_t)i * 6;
        float4 a, b;
        a.x = xr[0]; a.y = xr[1]; a.z = xr[2]; a.w = xr[3];
        b.x = xr[4]; b.y = xr[5]; b.z = 0.f; b.w = 0.f;
        float4* o = (float4*)(xpad + (size_t)i * 8);
        o[0] = a; o[1] = b;
    }
}

__global__ void count_kernel(const int* __restrict__ dst, int* __restrict__ counts) {
    int e = blockIdx.x * blockDim.x + threadIdx.x;
    if (e < N_EDGES) atomicAdd(&counts[dst[e]], 1);
}

__global__ void assign_kernel(const int* __restrict__ counts, int* __restrict__ row_start,
                              int* __restrict__ cursor, int* __restrict__ total) {
    int i = blockIdx.x * blockDim.x + threadIdx.x;
    if (i < N_NODES) {
        int c = counts[i];
        int s = atomicAdd(total, c);   // row order arbitrary; rows contiguous — fine
        row_start[i] = s;
        cursor[i] = s;
    }
}

__global__ void fill_kernel(const int* __restrict__ src, const int* __restrict__ dst,
                            const float* __restrict__ w, int* __restrict__ cursor,
                            uint2* __restrict__ rec) {
    int e = blockIdx.x * blockDim.x + threadIdx.x;
    if (e < N_EDGES) {
        int pos = atomicAdd(&cursor[dst[e]], 1);
        uint2 r;
        r.x = (uint32_t)src[e];
        r.y = __float_as_uint(w[e]);
        rec[pos] = r;
    }
}

// ---------------------------------------------------------------------------
// Fused layer: agg = segsum(w_e * x[src]); y = act(agg@Wrel + b + x@Wroot)
// One thread per node; x buffers padded to SIN (mult of 4) so the gather is
// pure float4 loads. Pad lanes are zeroed on write, so vector accumulation
// over pads is safe (they are never consumed by the dense part: i < DIN).
// ---------------------------------------------------------------------------

template<int DIN, int SIN, int DOUT, int SOUT, bool LAST>
__global__ void layer_kernel(const float* __restrict__ xin,
                             const uint2* __restrict__ rec,
                             const int* __restrict__ row_start,
                             const int* __restrict__ counts,
                             const float* __restrict__ wrel,
                             const float* __restrict__ brel,
                             const float* __restrict__ wroot,
                             float* __restrict__ xout) {
    __shared__ float s_wrel[DIN * DOUT];
    __shared__ float s_wroot[DIN * DOUT];
    __shared__ float s_b[DOUT];
    for (int t = threadIdx.x; t < DIN * DOUT; t += blockDim.x) {
        s_wrel[t]  = wrel[t];
        s_wroot[t] = wroot[t];
    }
    if (threadIdx.x < DOUT) s_b[threadIdx.x] = brel[threadIdx.x];
    __syncthreads();

    int node = blockIdx.x * blockDim.x + threadIdx.x;
    if (node >= N_NODES) return;

    constexpr int NV = SIN / 4;
    float4 acc[NV];
    #pragma unroll
    for (int v = 0; v < NV; ++v) acc[v] = make_float4(0.f, 0.f, 0.f, 0.f);

    const int s = row_start[node];
    const int e = s + counts[node];
    for (int k = s; k < e; ++k) {
        uint2 r = rec[k];
        float w = __uint_as_float(r.y);
        const float4* xs = (const float4*)(xin + (size_t)r.x * SIN);
        #pragma unroll
        for (int v = 0; v < NV; ++v) {
            float4 xv = xs[v];
            acc[v].x += w * xv.x;
            acc[v].y += w * xv.y;
            acc[v].z += w * xv.z;
            acc[v].w += w * xv.w;
        }
    }

    float4 self[NV];
    const float4* xsf = (const float4*)(xin + (size_t)node * SIN);
    #pragma unroll
    for (int v = 0; v < NV; ++v) self[v] = xsf[v];

    const float* accf  = (const float*)acc;
    const float* selff = (const float*)self;

    float out[DOUT];
    #pragma unroll
    for (int j = 0; j < DOUT; ++j) out[j] = s_b[j];
    #pragma unroll
    for (int i = 0; i < DIN; ++i) {
        float a  = accf[i];
        float sf = selff[i];
        #pragma unroll
        for (int j = 0; j < DOUT; ++j)
            out[j] += a * s_wrel[i * DOUT + j] + sf * s_wroot[i * DOUT + j];
    }

    if (LAST) {
        float m = out[0];
        #pragma unroll
        for (int j = 1; j < DOUT; ++j) m = fmaxf(m, out[j]);
        float sum = 0.f;
        #pragma unroll
        for (int j = 0; j < DOUT; ++j) { out[j] = __expf(out[j] - m); sum += out[j]; }
        float inv = 1.f / sum;
        #pragma unroll
        for (int j = 0; j < DOUT; ++j) xout[(size_t)node * SOUT + j] = out[j] * inv;
    } else {
        #pragma unroll
        for (int j = 0; j < DOUT; ++j)
            xout[(size_t)node * SOUT + j] = fmaxf(out[j], 0.f);
        #pragma unroll
        for (int j = DOUT; j < SOUT; ++j)       // zero pads: read as float4 next layer
            xout[(size_t)node * SOUT + j] = 0.f;
    }
}

// ---------------------------------------------------------------------------

extern "C" void kernel_launch(void* const* d_in, const int* in_sizes, int n_in,
                              void* d_out, int out_size, void* d_ws, size_t ws_size,
                              hipStream_t stream) {
    const float* x  = (const float*)d_in[0];
    const int*   ei = (const int*)d_in[1];
    const float* ew = (const float*)d_in[2];
    const float* wrel[5]  = { (const float*)d_in[3], (const float*)d_in[6],
                              (const float*)d_in[9], (const float*)d_in[12],
                              (const float*)d_in[15] };
    const float* brel[5]  = { (const float*)d_in[4], (const float*)d_in[7],
                              (const float*)d_in[10], (const float*)d_in[13],
                              (const float*)d_in[16] };
    const float* wroot[5] = { (const float*)d_in[5], (const float*)d_in[8],
                              (const float*)d_in[11], (const float*)d_in[14],
                              (const float*)d_in[17] };

    char* ws = (char*)d_ws;
    size_t off = 0;
    auto alloc = [&](size_t bytes) -> void* {
        void* p = ws + off;
        off += (bytes + 255) & ~(size_t)255;
        return p;
    };
    int*   counts    = (int*)alloc((size_t)N_NODES * 4);
    int*   row_start = (int*)alloc((size_t)N_NODES * 4);
    int*   cursor    = (int*)alloc((size_t)N_NODES * 4);
    int*   total     = (int*)alloc(4);
    uint2* rec       = (uint2*)alloc((size_t)N_EDGES * 8);
    float* bufA      = (float*)alloc((size_t)N_NODES * 20 * 4);
    float* bufB      = (float*)alloc((size_t)N_NODES * 20 * 4);
    // total ≈ 43 MB of ws

    const int* srcv = ei;            // edge_index row 0
    const int* dstv = ei + N_EDGES;  // edge_index row 1

    const int B  = 256;
    const int gN = (N_NODES + B - 1) / B;
    const int gE = (N_EDGES + B - 1) / B;

    pad_x_kernel <<<gN, B, 0, stream>>>(x, bufA, counts, total);
    count_kernel <<<gE, B, 0, stream>>>(dstv, counts);
    assign_kernel<<<gN, B, 0, stream>>>(counts, row_start, cursor, total);
    fill_kernel  <<<gE, B, 0, stream>>>(srcv, dstv, ew, cursor, rec);

    // dims: 6 -> 20 -> 15 -> 10 -> 5 -> 2 (softmax)
    layer_kernel< 6,  8, 20, 20, false><<<gN, B, 0, stream>>>(
        bufA, rec, row_start, counts, wrel[0], brel[0], wroot[0], bufB);
    layer_kernel<20, 20, 15, 16, false><<<gN, B, 0, stream>>>(
        bufB, rec, row_start, counts, wrel[1], brel[1], wroot[1], bufA);
    layer_kernel<15, 16, 10, 12, false><<<gN, B, 0, stream>>>(
        bufA, rec, row_start, counts, wrel[2], brel[2], wroot[2], bufB);
    layer_kernel<10, 12,  5,  8, false><<<gN, B, 0, stream>>>(
        bufB, rec, row_start, counts, wrel[3], brel[3], wroot[3], bufA);
    layer_kernel< 5,  8,  2,  2, true ><<<gN, B, 0, stream>>>(
        bufA, rec, row_start, counts, wrel[4], brel[4], wroot[4], (float*)d_out);
}